// Round 2
// baseline (1602.518 us; speedup 1.0000x reference)
//
#include <hip/hip_runtime.h>

#define Himg 135
#define Wimg 240
#define Bimg 128
#define Cimg 3
#define BCN (Bimg*Cimg)
#define HW (Himg*Wimg)
#define CHW (Cimg*HW)
#define TOTAL (BCN*HW)
#define EPSF 1e-10f

typedef float fvec4 __attribute__((ext_vector_type(4)));

// ws layout (floats): [0,384) num, [384,768) den, [768,896) per-image dots

template<int N>
__global__ __launch_bounds__(256, 3) void vif_scale_kernel(
    const float* __restrict__ recons,
    const float* __restrict__ x,
    float* __restrict__ numg,
    float* __restrict__ deng)
{
  constexpr int OW  = Wimg - N + 1;         // valid output width
  constexpr int OV  = Himg - N + 1;         // valid output height
  constexpr int OCb = 16;                   // output cols per block
  constexpr int NB  = (OW + OCb - 1)/OCb;   // col bands
  constexpr int IWb = OCb + N - 1;          // input cols needed
  constexpr int F4  = (IWb + 3)/4;          // float4 loads per row per array
  constexpr int RS  = 5*OCb + 8;            // LDS row stride (floats); +8 pad
                                            // -> 2-row lane stride 704B ≡ 64 mod 128: b128 conflict-free
  constexpr int ITEMS = 4*((OV+1)/2);       // (rowpair, colquad) work items

  __shared__ float uwin[N];
  __shared__ float hrows[Himg*RS];          // [row][chan][16] (+pad)
  __shared__ float red[8];

  const int tid  = threadIdx.x;
  const int blk  = blockIdx.x;
  const int band = blk % NB;
  const int bc   = blk / NB;
  const int x0   = band*OCb;

  if (tid == 0) {
    float w1[N]; float ssum = 0.f;
    const float sig = (float)N / 5.0f;
    const float inv = 1.0f / (2.0f*sig*sig);
    #pragma unroll
    for (int i = 0; i < N; ++i) {
      float d = (float)(i - N/2);
      w1[i] = __expf(-d*d*inv) ;
      ssum += w1[i];
    }
    // use precise expf to match reference numerics
    ssum = 0.f;
    #pragma unroll
    for (int i = 0; i < N; ++i) {
      float d = (float)(i - N/2);
      w1[i] = expf(-d*d*inv);
      ssum += w1[i];
    }
    #pragma unroll
    for (int i = 0; i < N; ++i) uwin[i] = w1[i]/ssum;
  }
  __syncthreads();

  float u[N];
  #pragma unroll
  for (int i = 0; i < N; ++i) u[i] = uwin[i];

  // ---------------- Phase 1: horizontal conv, one thread per row ----------------
  if (tid < Himg) {
    const int r = tid;
    float rv[4*F4], pv[4*F4];
    const int base = bc*HW + r*Wimg + x0;
    #pragma unroll
    for (int g = 0; g < F4; ++g) {
      int idx = base + 4*g;
      if (idx > TOTAL-4) idx = TOTAL-4;     // only reachable on very last row/band
      fvec4 a = *(const fvec4*)(recons + idx);
      fvec4 b = *(const fvec4*)(x + idx);
      #pragma unroll
      for (int k = 0; k < 4; ++k) { rv[4*g+k] = a[k]; pv[4*g+k] = b[k]; }
    }
    float* hb = hrows + r*RS;

    auto convWrite = [&](const float* w, int c) {
      float acc[OCb];
      #pragma unroll
      for (int o = 0; o < OCb; ++o) {
        float s = 0.f;
        #pragma unroll
        for (int i = 0; i < N; ++i) s = fmaf(u[i], w[o+i], s);
        acc[o] = s;
      }
      #pragma unroll
      for (int j = 0; j < OCb/4; ++j) {
        fvec4 v; v[0]=acc[4*j]; v[1]=acc[4*j+1]; v[2]=acc[4*j+2]; v[3]=acc[4*j+3];
        *(fvec4*)(hb + c*OCb + 4*j) = v;
      }
    };

    float ww[4*F4];
    convWrite(rv, 0);                                   // mu1 source
    convWrite(pv, 1);                                   // mu2 source
    #pragma unroll
    for (int k = 0; k < 4*F4; ++k) ww[k] = rv[k]*pv[k];
    convWrite(ww, 4);                                   // E[rp]
    #pragma unroll
    for (int k = 0; k < 4*F4; ++k) ww[k] = rv[k]*rv[k];
    convWrite(ww, 2);                                   // E[r^2]
    #pragma unroll
    for (int k = 0; k < 4*F4; ++k) ww[k] = pv[k]*pv[k];
    convWrite(ww, 3);                                   // E[p^2]
  }
  __syncthreads();

  // ---------------- Phase 2: vertical conv + pointwise ----------------
  float numAcc = 0.f, denAcc = 0.f;

  for (int it = tid; it < ITEMS; it += 256) {
    const int q  = it & 3;
    const int rp = it >> 2;
    const int j0 = 2*rp;                    // j0 <= OV-1 guaranteed
    const float* vb = hrows + j0*RS + q*4;

    float a0[5][4], a1[5][4];
    #pragma unroll
    for (int c = 0; c < 5; ++c)
      #pragma unroll
      for (int k = 0; k < 4; ++k) { a0[c][k] = 0.f; a1[c][k] = 0.f; }

    #pragma unroll
    for (int i = 0; i < N; ++i) {
      fvec4 v[5];
      #pragma unroll
      for (int c = 0; c < 5; ++c) v[c] = *(const fvec4*)(vb + i*RS + c*OCb);
      const float w0 = u[i];
      #pragma unroll
      for (int c = 0; c < 5; ++c)
        #pragma unroll
        for (int k = 0; k < 4; ++k) a0[c][k] = fmaf(w0, v[c][k], a0[c][k]);
      if (i >= 1) {
        const float w1 = u[i-1];
        #pragma unroll
        for (int c = 0; c < 5; ++c)
          #pragma unroll
          for (int k = 0; k < 4; ++k) a1[c][k] = fmaf(w1, v[c][k], a1[c][k]);
      }
    }
    const bool row1 = (j0 + 1 < OV);
    if (row1) {
      fvec4 v[5];
      #pragma unroll
      for (int c = 0; c < 5; ++c) v[c] = *(const fvec4*)(vb + N*RS + c*OCb);
      const float w1 = u[N-1];
      #pragma unroll
      for (int c = 0; c < 5; ++c)
        #pragma unroll
        for (int k = 0; k < 4; ++k) a1[c][k] = fmaf(w1, v[c][k], a1[c][k]);
    }

    auto pointwise = [&](float (&a)[5][4]) {
      #pragma unroll
      for (int k = 0; k < 4; ++k) {
        if (x0 + 4*q + k < OW) {
          float mu1 = a[0][k], mu2 = a[1][k];
          float sGT = fmaxf(a[2][k] - mu1*mu1, 0.f);
          float sP  = fmaxf(a[3][k] - mu2*mu2, 0.f);
          float sGP = a[4][k] - mu1*mu2;
          float g  = sGP / (sGT + EPSF);
          float sv = sP - g*sGP;
          if (sGT < EPSF) { g = 0.f; sv = sP; sGT = 0.f; }
          if (sP  < EPSF) { g = 0.f; sv = 0.f; }
          if (g < 0.f)    { sv = sP; g = 0.f; }
          if (sv <= EPSF) sv = EPSF;
          numAcc += __log10f(1.f + g*g*sGT/(sv + 2.0f));
          denAcc += __log10f(1.f + sGT*0.5f);
        }
      }
    };
    pointwise(a0);
    if (row1) pointwise(a1);
  }

  // ---------------- block reduction ----------------
  #pragma unroll
  for (int off = 32; off > 0; off >>= 1) {
    numAcc += __shfl_down(numAcc, off);
    denAcc += __shfl_down(denAcc, off);
  }
  const int lane = tid & 63, wid = tid >> 6;
  if (lane == 0) { red[wid] = numAcc; red[4+wid] = denAcc; }
  __syncthreads();
  if (tid == 0) {
    atomicAdd(&numg[bc], red[0]+red[1]+red[2]+red[3]);
    atomicAdd(&deng[bc], red[4]+red[5]+red[6]+red[7]);
  }
}

// per-image dot, split 8 ways: dots[b] += partial of sum_i (x-r)*W
__global__ __launch_bounds__(256) void dot_kernel(
    const float* __restrict__ r, const float* __restrict__ x,
    const float* __restrict__ Wl, float* __restrict__ dots)
{
  const int b  = blockIdx.x >> 3;
  const int ch = blockIdx.x & 7;
  constexpr int Q = CHW/4;            // 24300 float4 groups
  constexpr int per = (Q + 7)/8;      // 3038
  const int i0 = ch*per;
  const int i1 = (i0 + per < Q) ? (i0 + per) : Q;
  const int tid = threadIdx.x;
  const fvec4* r4 = (const fvec4*)(r + (size_t)b*CHW);
  const fvec4* x4 = (const fvec4*)(x + (size_t)b*CHW);
  const fvec4* w4 = (const fvec4*)Wl;
  float acc = 0.f;
  for (int i = i0 + tid; i < i1; i += 256) {
    fvec4 rv = r4[i], xv = x4[i], wv = w4[i];
    acc += (xv[0]-rv[0])*wv[0] + (xv[1]-rv[1])*wv[1]
         + (xv[2]-rv[2])*wv[2] + (xv[3]-rv[3])*wv[3];
  }
  #pragma unroll
  for (int off = 32; off > 0; off >>= 1) acc += __shfl_down(acc, off);
  __shared__ float red[4];
  const int lane = tid & 63, wid = tid >> 6;
  if (lane == 0) red[wid] = acc;
  __syncthreads();
  if (tid == 0) atomicAdd(&dots[b], red[0]+red[1]+red[2]+red[3]);
}

__global__ __launch_bounds__(128) void finalize_kernel(
    const float* __restrict__ ws, float* __restrict__ out)
{
  __shared__ float s1[128], s2[128];
  const int t = threadIdx.x;
  float d = ws[768 + t];
  float psq = d*d;
  float vimg = 0.f;
  #pragma unroll
  for (int c = 0; c < 3; ++c) {
    int bc = t*3 + c;
    vimg += ws[bc] / ws[384 + bc];
  }
  float rl = 1.f - vimg * (1.f/3.f);
  s1[t] = psq; s2[t] = rl;
  __syncthreads();
  for (int off = 64; off > 0; off >>= 1) {
    if (t < off) { s1[t] += s1[t+off]; s2[t] += s2[t+off]; }
    __syncthreads();
  }
  if (t == 0) {
    float pred = s1[0] * (1.f/128.f);
    float rec  = s2[0] * (1.f/128.f);
    out[0] = pred + rec;
    out[1] = rec;
    out[2] = pred;
  }
}

extern "C" void kernel_launch(void* const* d_in, const int* in_sizes, int n_in,
                              void* d_out, int out_size, void* d_ws, size_t ws_size,
                              hipStream_t stream) {
  const float* recons = (const float*)d_in[0];
  const float* x      = (const float*)d_in[1];
  const float* Wl     = (const float*)d_in[2];
  float* ws  = (float*)d_ws;
  float* out = (float*)d_out;

  hipMemsetAsync(d_ws, 0, 896*sizeof(float), stream);

  dot_kernel<<<Bimg*8, 256, 0, stream>>>(recons, x, Wl, ws + 768);

  vif_scale_kernel<17><<<BCN*14, 256, 0, stream>>>(recons, x, ws, ws + 384);
  vif_scale_kernel< 9><<<BCN*15, 256, 0, stream>>>(recons, x, ws, ws + 384);
  vif_scale_kernel< 5><<<BCN*15, 256, 0, stream>>>(recons, x, ws, ws + 384);
  vif_scale_kernel< 3><<<BCN*15, 256, 0, stream>>>(recons, x, ws, ws + 384);

  finalize_kernel<<<1, 128, 0, stream>>>(ws, out);
}

// Round 3
// 511.427 us; speedup vs baseline: 3.1334x; 3.1334x over previous
//
#include <hip/hip_runtime.h>

#define Himg 135
#define Wimg 240
#define Bimg 128
#define Cimg 3
#define BCN (Bimg*Cimg)
#define HW (Himg*Wimg)
#define CHW (Cimg*HW)
#define TOTAL (BCN*HW)
#define EPSF 1e-10f

typedef float fvec4 __attribute__((ext_vector_type(4)));

// ws layout (floats): [0,384) num, [384,768) den, [768,896) per-image dots

// Horizontal 4-wide conv. Arrays by reference + forceinline => SROA keeps
// everything in VGPRs (R2's pointer-decay lambda spilled 4 GB to scratch).
template<int NN, int LEN>
__device__ __forceinline__ fvec4 hconv4(const float (&u)[NN], const float (&w)[LEN]) {
  fvec4 o;
  #pragma unroll
  for (int k = 0; k < 4; ++k) {
    float s = 0.f;
    #pragma unroll
    for (int i = 0; i < NN; ++i) s = fmaf(u[i], w[k + i], s);
    o[k] = s;
  }
  return o;
}

template<int N>
__global__ __launch_bounds__(256) void vif_scale_kernel(
    const float* __restrict__ recons,
    const float* __restrict__ xim,
    float* __restrict__ numg,
    float* __restrict__ deng)
{
  constexpr int OW   = Wimg - N + 1;          // valid output width
  constexpr int OV   = Himg - N + 1;          // valid output height
  constexpr int OCb  = 16;                    // output cols per block
  constexpr int NB   = (OW + OCb - 1) / OCb;  // col bands
  constexpr int LD4  = (N + 6) / 4;           // fvec4 loads per item (>= N+3 floats)
  constexpr int RS   = 5 * OCb + 8;           // LDS row stride (floats), +8 pad
  constexpr int IT1  = Himg * 4;              // phase-1 items: (row, quad)
  constexpr int IT2  = 4 * ((OV + 1) / 2);    // phase-2 items: (rowpair, quad)

  __shared__ float uwin[N];
  __shared__ float hrows[Himg * RS];          // [row][chan(5)][16] + pad
  __shared__ float red[8];

  const int tid  = threadIdx.x;
  const int blk  = blockIdx.x;
  const int band = blk % NB;
  const int bc   = blk / NB;
  const int x0   = band * OCb;

  if (tid == 0) {
    float w1[N]; float ssum = 0.f;
    const float sig = (float)N / 5.0f;
    const float inv = 1.0f / (2.0f * sig * sig);
    #pragma unroll
    for (int i = 0; i < N; ++i) {
      float d = (float)(i - N / 2);
      w1[i] = expf(-d * d * inv);
      ssum += w1[i];
    }
    #pragma unroll
    for (int i = 0; i < N; ++i) uwin[i] = w1[i] / ssum;
  }
  __syncthreads();

  float u[N];
  #pragma unroll
  for (int i = 0; i < N; ++i) u[i] = uwin[i];

  // ---------------- Phase 1: horizontal conv, item = (row, col-quad) ----------------
  for (int it = tid; it < IT1; it += 256) {
    const int r = it >> 2;
    const int q = it & 3;
    float rr[4 * LD4], pp[4 * LD4], tt[4 * LD4];
    const int base = bc * HW + r * Wimg + x0 + 4 * q;   // 16B-aligned
    #pragma unroll
    for (int g = 0; g < LD4; ++g) {
      int idx = base + 4 * g;
      if (idx > TOTAL - 4) idx = TOTAL - 4;   // tail clamp; affected outputs are masked
      fvec4 a = *(const fvec4*)(recons + idx);
      fvec4 b = *(const fvec4*)(xim + idx);
      #pragma unroll
      for (int k = 0; k < 4; ++k) { rr[4*g+k] = a[k]; pp[4*g+k] = b[k]; }
    }
    float* hb = hrows + r * RS + q * 4;
    *(fvec4*)(hb + 0 * OCb) = hconv4<N>(u, rr);
    *(fvec4*)(hb + 1 * OCb) = hconv4<N>(u, pp);
    #pragma unroll
    for (int k = 0; k < 4 * LD4; ++k) tt[k] = rr[k] * rr[k];
    *(fvec4*)(hb + 2 * OCb) = hconv4<N>(u, tt);
    #pragma unroll
    for (int k = 0; k < 4 * LD4; ++k) tt[k] = pp[k] * pp[k];
    *(fvec4*)(hb + 3 * OCb) = hconv4<N>(u, tt);
    #pragma unroll
    for (int k = 0; k < 4 * LD4; ++k) tt[k] = rr[k] * pp[k];
    *(fvec4*)(hb + 4 * OCb) = hconv4<N>(u, tt);
  }
  __syncthreads();

  // ---------------- Phase 2: vertical conv + pointwise, item = (rowpair, quad) ----
  float numAcc = 0.f, denAcc = 0.f;

  for (int it = tid; it < IT2; it += 256) {
    const int q  = it & 3;
    const int rp = it >> 2;
    const int j0 = 2 * rp;
    const int vb = j0 * RS + q * 4;

    fvec4 a0[5], a1[5];
    #pragma unroll
    for (int c = 0; c < 5; ++c) {
      #pragma unroll
      for (int k = 0; k < 4; ++k) { a0[c][k] = 0.f; a1[c][k] = 0.f; }
    }

    #pragma unroll
    for (int i = 0; i < N; ++i) {
      fvec4 v[5];
      #pragma unroll
      for (int c = 0; c < 5; ++c) v[c] = *(const fvec4*)(hrows + vb + i * RS + c * OCb);
      const float w0 = u[i];
      #pragma unroll
      for (int c = 0; c < 5; ++c)
        #pragma unroll
        for (int k = 0; k < 4; ++k) a0[c][k] = fmaf(w0, v[c][k], a0[c][k]);
      if (i >= 1) {
        const float w1 = u[i - 1];
        #pragma unroll
        for (int c = 0; c < 5; ++c)
          #pragma unroll
          for (int k = 0; k < 4; ++k) a1[c][k] = fmaf(w1, v[c][k], a1[c][k]);
      }
    }
    const bool row1 = (j0 + 1 < OV);
    if (row1) {
      fvec4 v[5];
      #pragma unroll
      for (int c = 0; c < 5; ++c) v[c] = *(const fvec4*)(hrows + vb + N * RS + c * OCb);
      const float w1 = u[N - 1];
      #pragma unroll
      for (int c = 0; c < 5; ++c)
        #pragma unroll
        for (int k = 0; k < 4; ++k) a1[c][k] = fmaf(w1, v[c][k], a1[c][k]);
    }

    #pragma unroll
    for (int rsel = 0; rsel < 2; ++rsel) {
      if (rsel == 1 && !row1) break;
      #pragma unroll
      for (int k = 0; k < 4; ++k) {
        if (x0 + 4 * q + k < OW) {
          float mu1 = (rsel ? a1[0][k] : a0[0][k]);
          float mu2 = (rsel ? a1[1][k] : a0[1][k]);
          float e2  = (rsel ? a1[2][k] : a0[2][k]);
          float e3  = (rsel ? a1[3][k] : a0[3][k]);
          float e4  = (rsel ? a1[4][k] : a0[4][k]);
          float sGT = fmaxf(e2 - mu1 * mu1, 0.f);
          float sP  = fmaxf(e3 - mu2 * mu2, 0.f);
          float sGP = e4 - mu1 * mu2;
          float g  = sGP / (sGT + EPSF);
          float sv = sP - g * sGP;
          if (sGT < EPSF) { g = 0.f; sv = sP; sGT = 0.f; }
          if (sP  < EPSF) { g = 0.f; sv = 0.f; }
          if (g < 0.f)    { sv = sP; g = 0.f; }
          if (sv <= EPSF) sv = EPSF;
          numAcc += __log10f(1.f + g * g * sGT / (sv + 2.0f));
          denAcc += __log10f(1.f + sGT * 0.5f);
        }
      }
    }
  }

  // ---------------- block reduction ----------------
  #pragma unroll
  for (int off = 32; off > 0; off >>= 1) {
    numAcc += __shfl_down(numAcc, off);
    denAcc += __shfl_down(denAcc, off);
  }
  const int lane = tid & 63, wid = tid >> 6;
  if (lane == 0) { red[wid] = numAcc; red[4 + wid] = denAcc; }
  __syncthreads();
  if (tid == 0) {
    atomicAdd(&numg[bc], red[0] + red[1] + red[2] + red[3]);
    atomicAdd(&deng[bc], red[4] + red[5] + red[6] + red[7]);
  }
}

// per-image dot, split 8 ways: dots[b] += partial of sum_i (x-r)*W
__global__ __launch_bounds__(256) void dot_kernel(
    const float* __restrict__ r, const float* __restrict__ x,
    const float* __restrict__ Wl, float* __restrict__ dots)
{
  const int b  = blockIdx.x >> 3;
  const int ch = blockIdx.x & 7;
  constexpr int Q = CHW / 4;
  constexpr int per = (Q + 7) / 8;
  const int i0 = ch * per;
  const int i1 = (i0 + per < Q) ? (i0 + per) : Q;
  const int tid = threadIdx.x;
  const fvec4* r4 = (const fvec4*)(r + (size_t)b * CHW);
  const fvec4* x4 = (const fvec4*)(x + (size_t)b * CHW);
  const fvec4* w4 = (const fvec4*)Wl;
  float acc = 0.f;
  for (int i = i0 + tid; i < i1; i += 256) {
    fvec4 rv = r4[i], xv = x4[i], wv = w4[i];
    acc += (xv[0] - rv[0]) * wv[0] + (xv[1] - rv[1]) * wv[1]
         + (xv[2] - rv[2]) * wv[2] + (xv[3] - rv[3]) * wv[3];
  }
  #pragma unroll
  for (int off = 32; off > 0; off >>= 1) acc += __shfl_down(acc, off);
  __shared__ float red[4];
  const int lane = tid & 63, wid = tid >> 6;
  if (lane == 0) red[wid] = acc;
  __syncthreads();
  if (tid == 0) atomicAdd(&dots[b], red[0] + red[1] + red[2] + red[3]);
}

__global__ __launch_bounds__(128) void finalize_kernel(
    const float* __restrict__ ws, float* __restrict__ out)
{
  __shared__ float s1[128], s2[128];
  const int t = threadIdx.x;
  float d = ws[768 + t];
  float psq = d * d;
  float vimg = 0.f;
  #pragma unroll
  for (int c = 0; c < 3; ++c) {
    int bc = t * 3 + c;
    vimg += ws[bc] / ws[384 + bc];
  }
  float rl = 1.f - vimg * (1.f / 3.f);
  s1[t] = psq; s2[t] = rl;
  __syncthreads();
  for (int off = 64; off > 0; off >>= 1) {
    if (t < off) { s1[t] += s1[t + off]; s2[t] += s2[t + off]; }
    __syncthreads();
  }
  if (t == 0) {
    float pred = s1[0] * (1.f / 128.f);
    float rec  = s2[0] * (1.f / 128.f);
    out[0] = pred + rec;
    out[1] = rec;
    out[2] = pred;
  }
}

extern "C" void kernel_launch(void* const* d_in, const int* in_sizes, int n_in,
                              void* d_out, int out_size, void* d_ws, size_t ws_size,
                              hipStream_t stream) {
  const float* recons = (const float*)d_in[0];
  const float* x      = (const float*)d_in[1];
  const float* Wl     = (const float*)d_in[2];
  float* ws  = (float*)d_ws;
  float* out = (float*)d_out;

  hipMemsetAsync(d_ws, 0, 896 * sizeof(float), stream);

  dot_kernel<<<Bimg * 8, 256, 0, stream>>>(recons, x, Wl, ws + 768);

  vif_scale_kernel<17><<<BCN * 14, 256, 0, stream>>>(recons, x, ws, ws + 384);
  vif_scale_kernel< 9><<<BCN * 15, 256, 0, stream>>>(recons, x, ws, ws + 384);
  vif_scale_kernel< 5><<<BCN * 15, 256, 0, stream>>>(recons, x, ws, ws + 384);
  vif_scale_kernel< 3><<<BCN * 15, 256, 0, stream>>>(recons, x, ws, ws + 384);

  finalize_kernel<<<1, 128, 0, stream>>>(ws, out);
}

// Round 5
// 408.580 us; speedup vs baseline: 3.9222x; 1.2517x over previous
//
#include <hip/hip_runtime.h>

#define Himg 135
#define Wimg 240
#define Bimg 128
#define Cimg 3
#define BCN (Bimg*Cimg)
#define HW (Himg*Wimg)
#define CHW (Cimg*HW)
#define TOTAL (BCN*HW)
#define EPSF 1e-10f

typedef float fvec4 __attribute__((ext_vector_type(4)));
typedef float fvec2 __attribute__((ext_vector_type(2)));

// VOP3P packed fp32: ALL operands are even-aligned VGPR pairs (R4 failed by
// passing a scalar float as src0). Default op_sel = lane-wise lo/lo, hi/hi,
// bit-identical to two v_fma_f32.
__device__ __forceinline__ void pk_fma(fvec2& a, fvec2 w, fvec2 v) {
  asm("v_pk_fma_f32 %0, %1, %2, %0" : "+v"(a) : "v"(w), "v"(v));
}
__device__ __forceinline__ fvec2 pk_mul(fvec2 w, fvec2 v) {
  fvec2 d;
  asm("v_pk_mul_f32 %0, %1, %2" : "=v"(d) : "v"(w), "v"(v));
  return d;
}

// Horizontal 4-wide conv; arrays by reference + forceinline => SROA-safe.
template<int NN, int LEN>
__device__ __forceinline__ fvec4 hconv4(const float (&u)[NN], const float (&w)[LEN]) {
  fvec4 o;
  #pragma unroll
  for (int k = 0; k < 4; ++k) {
    float s = 0.f;
    #pragma unroll
    for (int i = 0; i < NN; ++i) s = fmaf(u[i], w[k + i], s);
    o[k] = s;
  }
  return o;
}

template<int N>
__global__ __launch_bounds__(256, 3) void vif_scale_kernel(
    const float* __restrict__ recons,
    const float* __restrict__ xim,
    float* __restrict__ numg,
    float* __restrict__ deng)
{
  constexpr int OW   = Wimg - N + 1;
  constexpr int OV   = Himg - N + 1;
  constexpr int OCb  = 16;
  constexpr int NB   = (OW + OCb - 1) / OCb;
  constexpr int LD4  = (N + 6) / 4;
  constexpr int RS   = 5 * OCb + 8;
  constexpr int IT1  = Himg * 4;
  constexpr int IT2  = 4 * ((OV + 1) / 2);

  __shared__ float uwin[N];
  __shared__ float hrows[Himg * RS];
  __shared__ float red[8];

  const int tid  = threadIdx.x;
  const int blk  = blockIdx.x;
  const int band = blk % NB;
  const int bc   = blk / NB;
  const int x0   = band * OCb;

  if (tid == 0) {
    float w1[N]; float ssum = 0.f;
    const float sig = (float)N / 5.0f;
    const float inv = 1.0f / (2.0f * sig * sig);
    #pragma unroll
    for (int i = 0; i < N; ++i) {
      float d = (float)(i - N / 2);
      w1[i] = expf(-d * d * inv);
      ssum += w1[i];
    }
    #pragma unroll
    for (int i = 0; i < N; ++i) uwin[i] = w1[i] / ssum;
  }
  __syncthreads();

  float u[N];
  #pragma unroll
  for (int i = 0; i < N; ++i) u[i] = uwin[i];

  // ---------------- Phase 1: horizontal conv, item = (row, col-quad) --------
  #pragma clang loop unroll(disable)
  for (int it = tid; it < IT1; it += 256) {
    const int r = it >> 2;
    const int q = it & 3;
    float rr[4 * LD4], pp[4 * LD4], tt[4 * LD4];
    const int base = bc * HW + r * Wimg + x0 + 4 * q;
    #pragma unroll
    for (int g = 0; g < LD4; ++g) {
      int idx = base + 4 * g;
      if (idx > TOTAL - 4) idx = TOTAL - 4;   // tail clamp; outputs masked
      fvec4 a = *(const fvec4*)(recons + idx);
      fvec4 b = *(const fvec4*)(xim + idx);
      #pragma unroll
      for (int k = 0; k < 4; ++k) { rr[4*g+k] = a[k]; pp[4*g+k] = b[k]; }
    }
    float* hb = hrows + r * RS + q * 4;
    *(fvec4*)(hb + 0 * OCb) = hconv4<N>(u, rr);
    *(fvec4*)(hb + 1 * OCb) = hconv4<N>(u, pp);
    #pragma unroll
    for (int k = 0; k < 4 * LD4; ++k) tt[k] = rr[k] * pp[k];
    *(fvec4*)(hb + 4 * OCb) = hconv4<N>(u, tt);
    #pragma unroll
    for (int k = 0; k < 4 * LD4; ++k) tt[k] = rr[k] * rr[k];
    *(fvec4*)(hb + 2 * OCb) = hconv4<N>(u, tt);
    #pragma unroll
    for (int k = 0; k < 4 * LD4; ++k) tt[k] = pp[k] * pp[k];
    *(fvec4*)(hb + 3 * OCb) = hconv4<N>(u, tt);
  }
  __syncthreads();

  // weight pairs for packed phase-2 math (phase-1 arrays are dead here;
  // register allocator overlaps them)
  fvec2 u2[N];
  #pragma unroll
  for (int i = 0; i < N; ++i) { u2[i][0] = u[i]; u2[i][1] = u[i]; }

  // ---------------- Phase 2: vertical conv (packed fp32) + pointwise --------
  float numAcc = 0.f, denAcc = 0.f;

  #pragma clang loop unroll(disable)
  for (int it = tid; it < IT2; it += 256) {
    const int q  = it & 3;
    const int rp = it >> 2;
    const int j0 = 2 * rp;
    const int vb = j0 * RS + q * 4;

    fvec2 a0[5][2], a1[5][2];

    // i = 0: init a0 via pk_mul
    {
      #pragma unroll
      for (int c = 0; c < 5; ++c) {
        fvec4 t = *(const fvec4*)(hrows + vb + 0 * RS + c * OCb);
        a0[c][0] = pk_mul(u2[0], __builtin_shufflevector(t, t, 0, 1));
        a0[c][1] = pk_mul(u2[0], __builtin_shufflevector(t, t, 2, 3));
      }
    }
    // i = 1 .. N-1
    #pragma unroll
    for (int i = 1; i < N; ++i) {
      fvec2 v2[5][2];
      #pragma unroll
      for (int c = 0; c < 5; ++c) {
        fvec4 t = *(const fvec4*)(hrows + vb + i * RS + c * OCb);
        v2[c][0] = __builtin_shufflevector(t, t, 0, 1);
        v2[c][1] = __builtin_shufflevector(t, t, 2, 3);
      }
      #pragma unroll
      for (int c = 0; c < 5; ++c) {
        pk_fma(a0[c][0], u2[i], v2[c][0]);
        pk_fma(a0[c][1], u2[i], v2[c][1]);
      }
      if (i == 1) {
        #pragma unroll
        for (int c = 0; c < 5; ++c) {
          a1[c][0] = pk_mul(u2[0], v2[c][0]);
          a1[c][1] = pk_mul(u2[0], v2[c][1]);
        }
      } else {
        #pragma unroll
        for (int c = 0; c < 5; ++c) {
          pk_fma(a1[c][0], u2[i - 1], v2[c][0]);
          pk_fma(a1[c][1], u2[i - 1], v2[c][1]);
        }
      }
    }
    const bool row1 = (j0 + 1 < OV);
    if (row1) {
      #pragma unroll
      for (int c = 0; c < 5; ++c) {
        fvec4 t = *(const fvec4*)(hrows + vb + N * RS + c * OCb);
        pk_fma(a1[c][0], u2[N - 1], __builtin_shufflevector(t, t, 0, 1));
        pk_fma(a1[c][1], u2[N - 1], __builtin_shufflevector(t, t, 2, 3));
      }
    }

    #pragma unroll
    for (int rsel = 0; rsel < 2; ++rsel) {
      if (rsel == 1 && !row1) break;
      #pragma unroll
      for (int k = 0; k < 4; ++k) {
        if (x0 + 4 * q + k < OW) {
          const int h = k >> 1, l = k & 1;
          float mu1 = (rsel ? a1[0][h][l] : a0[0][h][l]);
          float mu2 = (rsel ? a1[1][h][l] : a0[1][h][l]);
          float e2  = (rsel ? a1[2][h][l] : a0[2][h][l]);
          float e3  = (rsel ? a1[3][h][l] : a0[3][h][l]);
          float e4  = (rsel ? a1[4][h][l] : a0[4][h][l]);
          float sGT = fmaxf(e2 - mu1 * mu1, 0.f);
          float sP  = fmaxf(e3 - mu2 * mu2, 0.f);
          float sGP = e4 - mu1 * mu2;
          float g  = sGP / (sGT + EPSF);
          float sv = sP - g * sGP;
          if (sGT < EPSF) { g = 0.f; sv = sP; sGT = 0.f; }
          if (sP  < EPSF) { g = 0.f; sv = 0.f; }
          if (g < 0.f)    { sv = sP; g = 0.f; }
          if (sv <= EPSF) sv = EPSF;
          numAcc += __log10f(1.f + g * g * sGT / (sv + 2.0f));
          denAcc += __log10f(1.f + sGT * 0.5f);
        }
      }
    }
  }

  // ---------------- block reduction ----------------
  #pragma unroll
  for (int off = 32; off > 0; off >>= 1) {
    numAcc += __shfl_down(numAcc, off);
    denAcc += __shfl_down(denAcc, off);
  }
  const int lane = tid & 63, wid = tid >> 6;
  if (lane == 0) { red[wid] = numAcc; red[4 + wid] = denAcc; }
  __syncthreads();
  if (tid == 0) {
    atomicAdd(&numg[bc], red[0] + red[1] + red[2] + red[3]);
    atomicAdd(&deng[bc], red[4] + red[5] + red[6] + red[7]);
  }
}

// per-image dot, split 8 ways
__global__ __launch_bounds__(256) void dot_kernel(
    const float* __restrict__ r, const float* __restrict__ x,
    const float* __restrict__ Wl, float* __restrict__ dots)
{
  const int b  = blockIdx.x >> 3;
  const int ch = blockIdx.x & 7;
  constexpr int Q = CHW / 4;
  constexpr int per = (Q + 7) / 8;
  const int i0 = ch * per;
  const int i1 = (i0 + per < Q) ? (i0 + per) : Q;
  const int tid = threadIdx.x;
  const fvec4* r4 = (const fvec4*)(r + (size_t)b * CHW);
  const fvec4* x4 = (const fvec4*)(x + (size_t)b * CHW);
  const fvec4* w4 = (const fvec4*)Wl;
  float acc = 0.f;
  for (int i = i0 + tid; i < i1; i += 256) {
    fvec4 rv = r4[i], xv = x4[i], wv = w4[i];
    acc += (xv[0] - rv[0]) * wv[0] + (xv[1] - rv[1]) * wv[1]
         + (xv[2] - rv[2]) * wv[2] + (xv[3] - rv[3]) * wv[3];
  }
  #pragma unroll
  for (int off = 32; off > 0; off >>= 1) acc += __shfl_down(acc, off);
  __shared__ float red[4];
  const int lane = tid & 63, wid = tid >> 6;
  if (lane == 0) red[wid] = acc;
  __syncthreads();
  if (tid == 0) atomicAdd(&dots[b], red[0] + red[1] + red[2] + red[3]);
}

__global__ __launch_bounds__(128) void finalize_kernel(
    const float* __restrict__ ws, float* __restrict__ out)
{
  __shared__ float s1[128], s2[128];
  const int t = threadIdx.x;
  float d = ws[768 + t];
  float psq = d * d;
  float vimg = 0.f;
  #pragma unroll
  for (int c = 0; c < 3; ++c) {
    int bc = t * 3 + c;
    vimg += ws[bc] / ws[384 + bc];
  }
  float rl = 1.f - vimg * (1.f / 3.f);
  s1[t] = psq; s2[t] = rl;
  __syncthreads();
  for (int off = 64; off > 0; off >>= 1) {
    if (t < off) { s1[t] += s1[t + off]; s2[t] += s2[t + off]; }
    __syncthreads();
  }
  if (t == 0) {
    float pred = s1[0] * (1.f / 128.f);
    float rec  = s2[0] * (1.f / 128.f);
    out[0] = pred + rec;
    out[1] = rec;
    out[2] = pred;
  }
}

extern "C" void kernel_launch(void* const* d_in, const int* in_sizes, int n_in,
                              void* d_out, int out_size, void* d_ws, size_t ws_size,
                              hipStream_t stream) {
  const float* recons = (const float*)d_in[0];
  const float* x      = (const float*)d_in[1];
  const float* Wl     = (const float*)d_in[2];
  float* ws  = (float*)d_ws;
  float* out = (float*)d_out;

  hipMemsetAsync(d_ws, 0, 896 * sizeof(float), stream);

  dot_kernel<<<Bimg * 8, 256, 0, stream>>>(recons, x, Wl, ws + 768);

  vif_scale_kernel<17><<<BCN * 14, 256, 0, stream>>>(recons, x, ws, ws + 384);
  vif_scale_kernel< 9><<<BCN * 15, 256, 0, stream>>>(recons, x, ws, ws + 384);
  vif_scale_kernel< 5><<<BCN * 15, 256, 0, stream>>>(recons, x, ws, ws + 384);
  vif_scale_kernel< 3><<<BCN * 15, 256, 0, stream>>>(recons, x, ws, ws + 384);

  finalize_kernel<<<1, 128, 0, stream>>>(ws, out);
}

// Round 6
// 372.913 us; speedup vs baseline: 4.2973x; 1.0956x over previous
//
#include <hip/hip_runtime.h>

#define Himg 135
#define Wimg 240
#define Bimg 128
#define Cimg 3
#define BCN (Bimg*Cimg)
#define HW (Himg*Wimg)
#define CHW (Cimg*HW)
#define TOTAL (BCN*HW)
#define EPSF 1e-10f

typedef float fvec4 __attribute__((ext_vector_type(4)));
typedef float fvec2 __attribute__((ext_vector_type(2)));

// VOP3P packed fp32: all operands are even-aligned VGPR pairs; default
// op_sel is lane-wise lo/lo hi/hi == two v_fma_f32 (bit-identical).
__device__ __forceinline__ void pk_fma(fvec2& a, fvec2 w, fvec2 v) {
  asm("v_pk_fma_f32 %0, %1, %2, %0" : "+v"(a) : "v"(w), "v"(v));
}
__device__ __forceinline__ fvec2 pk_mul(fvec2 w, fvec2 v) {
  fvec2 d;
  asm("v_pk_mul_f32 %0, %1, %2" : "=v"(d) : "v"(w), "v"(v));
  return d;
}
__device__ __forceinline__ fvec2 lo2(fvec4 t) { return __builtin_shufflevector(t, t, 0, 1); }
__device__ __forceinline__ fvec2 hi2(fvec4 t) { return __builtin_shufflevector(t, t, 2, 3); }

// Compile-time exp: double Taylor; |arg| <= ~2.8 for all our windows, so
// cancellation error ~1e-14 relative — far below the fp32 rounding of the
// reference's np.exp(float32). Weights land within 1 ulp of the reference.
constexpr double cexp(double x) {
  double s = 1.0, t = 1.0;
  for (int i = 1; i < 48; ++i) { t *= x / (double)i; s += t; }
  return s;
}
template<int N>
struct GaussW {
  float w[N];
  constexpr GaussW() : w{} {
    const float sig = (float)N / 5.0f;
    const float inv = 1.0f / (2.0f * sig * sig);
    float ws[N] = {};
    float ssum = 0.f;
    for (int i = 0; i < N; ++i) {
      float d = (float)(i - N / 2);
      ws[i] = (float)cexp((double)(-(d * d) * inv));
      ssum += ws[i];
    }
    for (int i = 0; i < N; ++i) w[i] = ws[i] / ssum;  // outer(w,w) == ref 2D win
  }
};

// Horizontal 4-wide conv; arrays by reference + forceinline => SROA-safe.
template<int NN, int LEN>
__device__ __forceinline__ fvec4 hconv4(const float (&u)[NN], const float (&w)[LEN]) {
  fvec4 o;
  #pragma unroll
  for (int k = 0; k < 4; ++k) {
    float s = 0.f;
    #pragma unroll
    for (int i = 0; i < NN; ++i) s = fmaf(u[i], w[k + i], s);
    o[k] = s;
  }
  return o;
}

// ws layout (floats): [0,384) num, [384,768) den, [768,896) per-image dots

template<int N>
__device__ __forceinline__ void vif_body(
    int b, const float* __restrict__ recons, const float* __restrict__ xim,
    float* __restrict__ numg, float* __restrict__ deng,
    float* lds, float* sred)
{
  constexpr int OW  = Wimg - N + 1;
  constexpr int OV  = Himg - N + 1;
  constexpr int OV0 = (OV + 1) / 2;          // chunk0 output rows
  constexpr int NB  = (OW + 15) / 16;
  constexpr int RS  = 88;                    // 5*16 + 8 pad (2-way bank alias = free)
  constexpr int LD4 = (N + 6) / 4;
  constexpr GaussW<N> GW{};

  const int tid   = threadIdx.x;
  const int band  = b % NB;
  const int t2    = b / NB;
  const int chunk = t2 & 1;
  const int bc    = t2 >> 1;
  const int x0    = band * 16;
  const int r0    = chunk ? OV0 : 0;               // first staged input row
  const int OVc   = chunk ? (OV - OV0) : OV0;      // output rows this chunk
  const int Rc    = OVc + N - 1;                   // staged input rows

  // ---------------- Phase 1: horizontal conv, item = (row, col-quad) --------
  #pragma clang loop unroll(disable)
  for (int it = tid; it < Rc * 4; it += 256) {
    const int r = it >> 2;
    const int q = it & 3;
    float rr[4 * LD4], pp[4 * LD4], tt[4 * LD4];
    const int base = bc * HW + (r0 + r) * Wimg + x0 + 4 * q;
    #pragma unroll
    for (int g = 0; g < LD4; ++g) {
      int idx = base + 4 * g;
      if (idx > TOTAL - 4) idx = TOTAL - 4;   // tail clamp; outputs masked
      fvec4 a  = *(const fvec4*)(recons + idx);
      fvec4 bb = *(const fvec4*)(xim + idx);
      #pragma unroll
      for (int k = 0; k < 4; ++k) { rr[4 * g + k] = a[k]; pp[4 * g + k] = bb[k]; }
    }
    float* hb = lds + r * RS + q * 4;
    *(fvec4*)(hb + 0 * 16) = hconv4<N>(GW.w, rr);
    *(fvec4*)(hb + 1 * 16) = hconv4<N>(GW.w, pp);
    #pragma unroll
    for (int k = 0; k < 4 * LD4; ++k) tt[k] = rr[k] * pp[k];
    *(fvec4*)(hb + 4 * 16) = hconv4<N>(GW.w, tt);
    #pragma unroll
    for (int k = 0; k < 4 * LD4; ++k) tt[k] = rr[k] * rr[k];
    *(fvec4*)(hb + 2 * 16) = hconv4<N>(GW.w, tt);
    #pragma unroll
    for (int k = 0; k < 4 * LD4; ++k) tt[k] = pp[k] * pp[k];
    *(fvec4*)(hb + 3 * 16) = hconv4<N>(GW.w, tt);
  }
  __syncthreads();

  // ---------------- Phase 2: vertical conv (packed) + pointwise -------------
  float numAcc = 0.f, denAcc = 0.f;
  const int IT2 = 4 * ((OVc + 1) / 2);

  if (tid < IT2) {
    const int q  = tid & 3;
    const int j0 = 2 * (tid >> 2);
    const bool row1 = (j0 + 1 < OVc);
    const int vbase = j0 * RS + q * 4;
    const int iN = row1 ? N : (N - 1);      // clamp: keep read in staged range

    fvec2 A0[5][2], A1[5][2];
    #pragma unroll
    for (int c = 0; c < 5; ++c) {
      const float* cp = lds + vbase + c * 16;
      fvec4 t0 = *(const fvec4*)cp;
      fvec2 w0 = {GW.w[0], GW.w[0]};
      A0[c][0] = pk_mul(w0, lo2(t0));
      A0[c][1] = pk_mul(w0, hi2(t0));
      #pragma unroll
      for (int i = 1; i < N; ++i) {
        fvec4 s = *(const fvec4*)(cp + i * RS);
        fvec2 wi = {GW.w[i], GW.w[i]};
        pk_fma(A0[c][0], wi, lo2(s));
        pk_fma(A0[c][1], wi, hi2(s));
        fvec2 wm = {GW.w[i - 1], GW.w[i - 1]};
        if (i == 1) { A1[c][0] = pk_mul(wm, lo2(s)); A1[c][1] = pk_mul(wm, hi2(s)); }
        else        { pk_fma(A1[c][0], wm, lo2(s));  pk_fma(A1[c][1], wm, hi2(s)); }
      }
      fvec4 e = *(const fvec4*)(cp + iN * RS);  // valid row; A1 discarded if !row1
      fvec2 wl = {GW.w[N - 1], GW.w[N - 1]};
      pk_fma(A1[c][0], wl, lo2(e));
      pk_fma(A1[c][1], wl, hi2(e));
    }

    #pragma unroll
    for (int rsel = 0; rsel < 2; ++rsel) {
      if (rsel == 1 && !row1) break;
      #pragma unroll
      for (int k = 0; k < 4; ++k) {
        if (x0 + 4 * q + k < OW) {
          const int h = k >> 1, l = k & 1;
          float mu1 = rsel ? A1[0][h][l] : A0[0][h][l];
          float mu2 = rsel ? A1[1][h][l] : A0[1][h][l];
          float e2  = rsel ? A1[2][h][l] : A0[2][h][l];
          float e3  = rsel ? A1[3][h][l] : A0[3][h][l];
          float e4  = rsel ? A1[4][h][l] : A0[4][h][l];
          float sGT = fmaxf(e2 - mu1 * mu1, 0.f);
          float sP  = fmaxf(e3 - mu2 * mu2, 0.f);
          float sGP = e4 - mu1 * mu2;
          float g  = __fdividef(sGP, sGT + EPSF);
          float sv = sP - g * sGP;
          if (sGT < EPSF) { g = 0.f; sv = sP; sGT = 0.f; }
          if (sP  < EPSF) { g = 0.f; sv = 0.f; }
          if (g < 0.f)    { sv = sP; g = 0.f; }
          if (sv <= EPSF) sv = EPSF;
          numAcc += __log10f(1.f + __fdividef(g * g * sGT, sv + 2.0f));
          denAcc += __log10f(1.f + sGT * 0.5f);
        }
      }
    }
  }

  // ---------------- block reduction ----------------
  #pragma unroll
  for (int off = 32; off > 0; off >>= 1) {
    numAcc += __shfl_down(numAcc, off);
    denAcc += __shfl_down(denAcc, off);
  }
  const int lane = tid & 63, wid = tid >> 6;
  if (lane == 0) { sred[wid] = numAcc; sred[4 + wid] = denAcc; }
  __syncthreads();
  if (tid == 0) {
    atomicAdd(&numg[bc], sred[0] + sred[1] + sred[2] + sred[3]);
    atomicAdd(&deng[bc], sred[4] + sred[5] + sred[6] + sred[7]);
  }
}

__device__ __forceinline__ void dot_body(
    int b, const float* __restrict__ r, const float* __restrict__ x,
    const float* __restrict__ Wl, float* __restrict__ dots, float* sred)
{
  const int img = b >> 3;
  const int ch  = b & 7;
  constexpr int Q = CHW / 4;
  constexpr int per = (Q + 7) / 8;
  const int i0 = ch * per;
  const int i1 = (i0 + per < Q) ? (i0 + per) : Q;
  const int tid = threadIdx.x;
  const fvec4* r4 = (const fvec4*)(r + (size_t)img * CHW);
  const fvec4* x4 = (const fvec4*)(x + (size_t)img * CHW);
  const fvec4* w4 = (const fvec4*)Wl;
  float acc = 0.f;
  for (int i = i0 + tid; i < i1; i += 256) {
    fvec4 rv = r4[i], xv = x4[i], wv = w4[i];
    acc += (xv[0] - rv[0]) * wv[0] + (xv[1] - rv[1]) * wv[1]
         + (xv[2] - rv[2]) * wv[2] + (xv[3] - rv[3]) * wv[3];
  }
  #pragma unroll
  for (int off = 32; off > 0; off >>= 1) acc += __shfl_down(acc, off);
  const int lane = tid & 63, wid = tid >> 6;
  if (lane == 0) sred[wid] = acc;
  __syncthreads();
  if (tid == 0) atomicAdd(&dots[img], sred[0] + sred[1] + sred[2] + sred[3]);
}

// block-range dispatch over all 4 scales + dot
constexpr int NB17 = 14, NB9 = 15, NB5 = 15, NB3 = 15;
constexpr int G17  = NB17 * 2 * BCN;
constexpr int G9   = G17 + NB9 * 2 * BCN;
constexpr int G5   = G9  + NB5 * 2 * BCN;
constexpr int G3   = G5  + NB3 * 2 * BCN;
constexpr int GALL = G3  + Bimg * 8;
constexpr int LDSB = 76 * 88 * 4;    // max staged rows (N=17 chunk0) * RS * 4B

__global__ __launch_bounds__(256, 5) void vif_fat_kernel(
    const float* __restrict__ recons, const float* __restrict__ xim,
    const float* __restrict__ Wl, float* __restrict__ ws)
{
  extern __shared__ float lds[];
  __shared__ float sred[8];
  float* numg = ws;
  float* deng = ws + 384;
  float* dots = ws + 768;
  const int b = blockIdx.x;
  if      (b < G17) vif_body<17>(b,       recons, xim, numg, deng, lds, sred);
  else if (b < G9)  vif_body< 9>(b - G17, recons, xim, numg, deng, lds, sred);
  else if (b < G5)  vif_body< 5>(b - G9,  recons, xim, numg, deng, lds, sred);
  else if (b < G3)  vif_body< 3>(b - G5,  recons, xim, numg, deng, lds, sred);
  else              dot_body(b - G3, recons, xim, Wl, dots, sred);
}

__global__ __launch_bounds__(128) void finalize_kernel(
    const float* __restrict__ ws, float* __restrict__ out)
{
  __shared__ float s1[128], s2[128];
  const int t = threadIdx.x;
  float d = ws[768 + t];
  float psq = d * d;
  float vimg = 0.f;
  #pragma unroll
  for (int c = 0; c < 3; ++c) {
    int bc = t * 3 + c;
    vimg += ws[bc] / ws[384 + bc];
  }
  float rl = 1.f - vimg * (1.f / 3.f);
  s1[t] = psq; s2[t] = rl;
  __syncthreads();
  for (int off = 64; off > 0; off >>= 1) {
    if (t < off) { s1[t] += s1[t + off]; s2[t] += s2[t + off]; }
    __syncthreads();
  }
  if (t == 0) {
    float pred = s1[0] * (1.f / 128.f);
    float rec  = s2[0] * (1.f / 128.f);
    out[0] = pred + rec;
    out[1] = rec;
    out[2] = pred;
  }
}

extern "C" void kernel_launch(void* const* d_in, const int* in_sizes, int n_in,
                              void* d_out, int out_size, void* d_ws, size_t ws_size,
                              hipStream_t stream) {
  const float* recons = (const float*)d_in[0];
  const float* x      = (const float*)d_in[1];
  const float* Wl     = (const float*)d_in[2];
  float* ws  = (float*)d_ws;
  float* out = (float*)d_out;

  hipMemsetAsync(d_ws, 0, 896 * sizeof(float), stream);

  vif_fat_kernel<<<GALL, 256, LDSB, stream>>>(recons, x, Wl, ws);

  finalize_kernel<<<1, 128, 0, stream>>>(ws, out);
}

// Round 7
// 345.679 us; speedup vs baseline: 4.6359x; 1.0788x over previous
//
#include <hip/hip_runtime.h>

#define Himg 135
#define Wimg 240
#define Bimg 128
#define Cimg 3
#define BCN (Bimg*Cimg)
#define HW (Himg*Wimg)
#define CHW (Cimg*HW)
#define TOTAL (BCN*HW)
#define EPSF 1e-10f

typedef float fvec4 __attribute__((ext_vector_type(4)));
typedef float fvec2 __attribute__((ext_vector_type(2)));

// VOP3P packed fp32. Weight operand in an SGPR pair ("s") — constants are
// wave-uniform; removes the per-tap v_mov rematerialization R6 paid with "v".
// Exactly one SGPR source per instruction (ISA rule ok).
__device__ __forceinline__ void pk_fma_s(fvec2& a, fvec2 w, fvec2 v) {
  asm("v_pk_fma_f32 %0, %1, %2, %0" : "+v"(a) : "s"(w), "v"(v));
}
__device__ __forceinline__ fvec2 pk_mul_s(fvec2 w, fvec2 v) {
  fvec2 d;
  asm("v_pk_mul_f32 %0, %1, %2" : "=v"(d) : "s"(w), "v"(v));
  return d;
}
__device__ __forceinline__ fvec2 lo2(fvec4 t) { return __builtin_shufflevector(t, t, 0, 1); }
__device__ __forceinline__ fvec2 hi2(fvec4 t) { return __builtin_shufflevector(t, t, 2, 3); }

// aligned fvec2 view of element pair (2m, 2m+1); m is unroll-constant
template<int G>
__device__ __forceinline__ fvec2 ivq(const fvec4 (&in)[G], int m) {
  return (m & 1) ? hi2(in[m >> 1]) : lo2(in[m >> 1]);
}

// Compile-time exp (double Taylor) — weights within 1 ulp of reference fp32.
constexpr double cexp(double x) {
  double s = 1.0, t = 1.0;
  for (int i = 1; i < 48; ++i) { t *= x / (double)i; s += t; }
  return s;
}
template<int N>
struct GaussW {
  float w[N];
  constexpr GaussW() : w{} {
    const float sig = (float)N / 5.0f;
    const float inv = 1.0f / (2.0f * sig * sig);
    float ws[N] = {};
    float ssum = 0.f;
    for (int i = 0; i < N; ++i) {
      float d = (float)(i - N / 2);
      ws[i] = (float)cexp((double)(-(d * d) * inv));
      ssum += ws[i];
    }
    for (int i = 0; i < N; ++i) w[i] = ws[i] / ssum;
  }
};

// Packed horizontal conv, 8 outputs, via shifted constexpr weight pairs:
// out[k] = sum_m P[k&1][m] (x) iv[(k>>1)+m]; all LDS/global inputs stay in
// their naturally aligned fvec2 views — zero shuffle movs.
template<int N, int G>
__device__ __forceinline__ void hconv8_store(
    const fvec4 (&in)[G],
    const fvec2 (&PE)[(N + 1) / 2],
    const fvec2 (&PO)[(N + 1) / 2],
    float* dst)
{
  constexpr int HN = (N + 1) / 2;
  float o[8];
  #pragma unroll
  for (int k = 0; k < 8; ++k) {
    const int s0 = k >> 1;
    fvec2 acc;
    if (k & 1) {
      acc = pk_mul_s(PO[0], ivq(in, s0));
      #pragma unroll
      for (int m = 1; m < HN; ++m) pk_fma_s(acc, PO[m], ivq(in, s0 + m));
    } else {
      acc = pk_mul_s(PE[0], ivq(in, s0));
      #pragma unroll
      for (int m = 1; m < HN; ++m) pk_fma_s(acc, PE[m], ivq(in, s0 + m));
    }
    o[k] = acc[0] + acc[1];
  }
  *(fvec4*)dst       = (fvec4){o[0], o[1], o[2], o[3]};
  *(fvec4*)(dst + 4) = (fvec4){o[4], o[5], o[6], o[7]};
}

// ws layout (floats): [0,384) num, [384,768) den, [768,896) per-image dots

template<int N>
__device__ __forceinline__ void vif_body(
    int b, const float* __restrict__ recons, const float* __restrict__ xim,
    float* __restrict__ numg, float* __restrict__ deng,
    float* lds, float* sred)
{
  constexpr int OW  = Wimg - N + 1;
  constexpr int OV  = Himg - N + 1;
  constexpr int OV0 = (OV + 1) / 2;
  constexpr int OCb = 24;
  constexpr int RS  = 5 * OCb + 4;          // 124 floats; 124%32=28 breaks row-bank aliasing
  constexpr int G   = (N + 10) / 4;         // fvec4 loads per 8-col item
  constexpr int HN  = (N + 1) / 2;
  constexpr GaussW<N> GW{};

  const int tid   = threadIdx.x;
  const int band  = b % 10;
  const int t2    = b / 10;
  const int chunk = t2 & 1;
  const int bc    = t2 >> 1;
  const int x0    = band * OCb;
  const int r0    = chunk ? OV0 : 0;
  const int OVc   = chunk ? (OV - OV0) : OV0;
  const int Rc    = OVc + N - 1;            // staged input rows (max 76)

  // ---------------- Phase 1: packed horizontal conv, item = (row, third) ----
  if (tid < Rc * 3) {
    // shifted weight pairs (constexpr -> s_mov literals, hoisted)
    fvec2 PE[HN], PO[HN];
    #pragma unroll
    for (int m = 0; m < HN; ++m) {
      PE[m][0] = GW.w[2 * m];
      PE[m][1] = (2 * m + 1 < N) ? GW.w[2 * m + 1] : 0.f;
      PO[m][0] = (m == 0) ? 0.f : GW.w[2 * m - 1];
      PO[m][1] = GW.w[2 * m];
    }
    const int r = tid / 3;
    const int h = tid - r * 3;
    const int base = bc * HW + (r0 + r) * Wimg + x0 + 8 * h;
    fvec4 rr4[G], pp4[G], tt4[G];
    if (base <= TOTAL - 4 * G) {
      #pragma unroll
      for (int g = 0; g < G; ++g) {
        rr4[g] = *(const fvec4*)(recons + base + 4 * g);
        pp4[g] = *(const fvec4*)(xim + base + 4 * g);
      }
    } else {                                 // only the very last row/band
      #pragma unroll
      for (int g = 0; g < G; ++g) {
        int idx = base + 4 * g;
        if (idx > TOTAL - 4) idx = TOTAL - 4;
        rr4[g] = *(const fvec4*)(recons + idx);
        pp4[g] = *(const fvec4*)(xim + idx);
      }
    }
    float* hb = lds + r * RS + 8 * h;
    hconv8_store<N, G>(rr4, PE, PO, hb + 0 * OCb);
    hconv8_store<N, G>(pp4, PE, PO, hb + 1 * OCb);
    #pragma unroll
    for (int g = 0; g < G; ++g) tt4[g] = rr4[g] * rr4[g];
    hconv8_store<N, G>(tt4, PE, PO, hb + 2 * OCb);
    #pragma unroll
    for (int g = 0; g < G; ++g) tt4[g] = pp4[g] * pp4[g];
    hconv8_store<N, G>(tt4, PE, PO, hb + 3 * OCb);
    #pragma unroll
    for (int g = 0; g < G; ++g) tt4[g] = rr4[g] * pp4[g];
    hconv8_store<N, G>(tt4, PE, PO, hb + 4 * OCb);
  }
  __syncthreads();

  // ---------------- Phase 2: packed vertical conv + pointwise ---------------
  float numAcc = 0.f, denAcc = 0.f;
  const int IT2 = 6 * ((OVc + 1) / 2);

  if (tid < IT2) {
    const int q  = tid % 6;
    const int j0 = 2 * (tid / 6);
    const bool row1 = (j0 + 1 < OVc);
    const int vbase = j0 * RS + q * 4;
    const int iN = row1 ? N : (N - 1);      // clamp read into staged range

    fvec2 A0[5][2], A1[5][2];
    #pragma unroll
    for (int c = 0; c < 5; ++c) {
      const float* cp = lds + vbase + c * OCb;
      fvec4 t0 = *(const fvec4*)cp;
      fvec2 w0 = {GW.w[0], GW.w[0]};
      A0[c][0] = pk_mul_s(w0, lo2(t0));
      A0[c][1] = pk_mul_s(w0, hi2(t0));
      #pragma unroll
      for (int i = 1; i < N; ++i) {
        fvec4 s = *(const fvec4*)(cp + i * RS);
        fvec2 wi = {GW.w[i], GW.w[i]};
        pk_fma_s(A0[c][0], wi, lo2(s));
        pk_fma_s(A0[c][1], wi, hi2(s));
        fvec2 wm = {GW.w[i - 1], GW.w[i - 1]};
        if (i == 1) { A1[c][0] = pk_mul_s(wm, lo2(s)); A1[c][1] = pk_mul_s(wm, hi2(s)); }
        else        { pk_fma_s(A1[c][0], wm, lo2(s));  pk_fma_s(A1[c][1], wm, hi2(s)); }
      }
      fvec4 e = *(const fvec4*)(cp + iN * RS);
      fvec2 wl = {GW.w[N - 1], GW.w[N - 1]};
      pk_fma_s(A1[c][0], wl, lo2(e));
      pk_fma_s(A1[c][1], wl, hi2(e));
    }

    #pragma unroll
    for (int rsel = 0; rsel < 2; ++rsel) {
      if (rsel == 1 && !row1) break;
      #pragma unroll
      for (int k = 0; k < 4; ++k) {
        if (x0 + 4 * q + k < OW) {
          const int hh = k >> 1, l = k & 1;
          float mu1 = rsel ? A1[0][hh][l] : A0[0][hh][l];
          float mu2 = rsel ? A1[1][hh][l] : A0[1][hh][l];
          float e2  = rsel ? A1[2][hh][l] : A0[2][hh][l];
          float e3  = rsel ? A1[3][hh][l] : A0[3][hh][l];
          float e4  = rsel ? A1[4][hh][l] : A0[4][hh][l];
          float sGT = fmaxf(e2 - mu1 * mu1, 0.f);
          float sP  = fmaxf(e3 - mu2 * mu2, 0.f);
          float sGP = e4 - mu1 * mu2;
          float g  = __fdividef(sGP, sGT + EPSF);
          float sv = sP - g * sGP;
          if (sGT < EPSF) { g = 0.f; sv = sP; sGT = 0.f; }
          if (sP  < EPSF) { g = 0.f; sv = 0.f; }
          if (g < 0.f)    { sv = sP; g = 0.f; }
          if (sv <= EPSF) sv = EPSF;
          numAcc += __log10f(1.f + __fdividef(g * g * sGT, sv + 2.0f));
          denAcc += __log10f(1.f + sGT * 0.5f);
        }
      }
    }
  }

  // ---------------- block reduction ----------------
  #pragma unroll
  for (int off = 32; off > 0; off >>= 1) {
    numAcc += __shfl_down(numAcc, off);
    denAcc += __shfl_down(denAcc, off);
  }
  const int lane = tid & 63, wid = tid >> 6;
  if (lane == 0) { sred[wid] = numAcc; sred[4 + wid] = denAcc; }
  __syncthreads();
  if (tid == 0) {
    atomicAdd(&numg[bc], sred[0] + sred[1] + sred[2] + sred[3]);
    atomicAdd(&deng[bc], sred[4] + sred[5] + sred[6] + sred[7]);
  }
}

__device__ __forceinline__ void dot_body(
    int b, const float* __restrict__ r, const float* __restrict__ x,
    const float* __restrict__ Wl, float* __restrict__ dots, float* sred)
{
  const int img = b >> 3;
  const int ch  = b & 7;
  constexpr int Q = CHW / 4;
  constexpr int per = (Q + 7) / 8;
  const int i0 = ch * per;
  const int i1 = (i0 + per < Q) ? (i0 + per) : Q;
  const int tid = threadIdx.x;
  const fvec4* r4 = (const fvec4*)(r + (size_t)img * CHW);
  const fvec4* x4 = (const fvec4*)(x + (size_t)img * CHW);
  const fvec4* w4 = (const fvec4*)Wl;
  float acc = 0.f;
  for (int i = i0 + tid; i < i1; i += 256) {
    fvec4 rv = r4[i], xv = x4[i], wv = w4[i];
    acc += (xv[0] - rv[0]) * wv[0] + (xv[1] - rv[1]) * wv[1]
         + (xv[2] - rv[2]) * wv[2] + (xv[3] - rv[3]) * wv[3];
  }
  #pragma unroll
  for (int off = 32; off > 0; off >>= 1) acc += __shfl_down(acc, off);
  const int lane = tid & 63, wid = tid >> 6;
  if (lane == 0) sred[wid] = acc;
  __syncthreads();
  if (tid == 0) atomicAdd(&dots[img], sred[0] + sred[1] + sred[2] + sred[3]);
}

constexpr int GSC  = 10 * 2 * BCN;           // blocks per scale (10 bands, 2 chunks)
constexpr int G17  = GSC;
constexpr int G9   = 2 * GSC;
constexpr int G5   = 3 * GSC;
constexpr int G3   = 4 * GSC;
constexpr int GALL = G3 + Bimg * 8;
constexpr int LDSB = 76 * 124 * 4;           // max staged rows × RS × 4B = 37696

__global__ __launch_bounds__(256, 4) void vif_fat_kernel(
    const float* __restrict__ recons, const float* __restrict__ xim,
    const float* __restrict__ Wl, float* __restrict__ ws)
{
  extern __shared__ float lds[];
  __shared__ float sred[8];
  float* numg = ws;
  float* deng = ws + 384;
  float* dots = ws + 768;
  const int b = blockIdx.x;
  if      (b < G17) vif_body<17>(b,      recons, xim, numg, deng, lds, sred);
  else if (b < G9)  vif_body< 9>(b - G17, recons, xim, numg, deng, lds, sred);
  else if (b < G5)  vif_body< 5>(b - G9,  recons, xim, numg, deng, lds, sred);
  else if (b < G3)  vif_body< 3>(b - G5,  recons, xim, numg, deng, lds, sred);
  else              dot_body(b - G3, recons, xim, Wl, dots, sred);
}

__global__ __launch_bounds__(128) void finalize_kernel(
    const float* __restrict__ ws, float* __restrict__ out)
{
  __shared__ float s1[128], s2[128];
  const int t = threadIdx.x;
  float d = ws[768 + t];
  float psq = d * d;
  float vimg = 0.f;
  #pragma unroll
  for (int c = 0; c < 3; ++c) {
    int bc = t * 3 + c;
    vimg += ws[bc] / ws[384 + bc];
  }
  float rl = 1.f - vimg * (1.f / 3.f);
  s1[t] = psq; s2[t] = rl;
  __syncthreads();
  for (int off = 64; off > 0; off >>= 1) {
    if (t < off) { s1[t] += s1[t + off]; s2[t] += s2[t + off]; }
    __syncthreads();
  }
  if (t == 0) {
    float pred = s1[0] * (1.f / 128.f);
    float rec  = s2[0] * (1.f / 128.f);
    out[0] = pred + rec;
    out[1] = rec;
    out[2] = pred;
  }
}

extern "C" void kernel_launch(void* const* d_in, const int* in_sizes, int n_in,
                              void* d_out, int out_size, void* d_ws, size_t ws_size,
                              hipStream_t stream) {
  const float* recons = (const float*)d_in[0];
  const float* x      = (const float*)d_in[1];
  const float* Wl     = (const float*)d_in[2];
  float* ws  = (float*)d_ws;
  float* out = (float*)d_out;

  hipMemsetAsync(d_ws, 0, 896 * sizeof(float), stream);

  vif_fat_kernel<<<GALL, 256, LDSB, stream>>>(recons, x, Wl, ws);

  finalize_kernel<<<1, 128, 0, stream>>>(ws, out);
}